// Round 13
// baseline (389.221 us; speedup 1.0000x reference)
//
#include <hip/hip_runtime.h>

typedef _Float16 f16;
typedef _Float16 f16x4 __attribute__((ext_vector_type(4)));
typedef _Float16 f16x8 __attribute__((ext_vector_type(8)));
typedef float f32x4 __attribute__((ext_vector_type(4)));

#define MFMA16(a, b, c) __builtin_amdgcn_mfma_f32_16x16x32_f16(a, b, c, 0, 0, 0)

// ---------------- Kernel 1: stats (2 rows/block) + W->f16 conversion -------
// blocks 0..2047   : per-(tensor,row-pair) mean / inv-std, 32 KB contiguous
// blocks 2048..2143: W -> f16 conversion (3 x 32 blocks)
__global__ __launch_bounds__(256) void stats_kernel(
    const float* __restrict__ content, const float* __restrict__ style,
    float* __restrict__ mu, float* __restrict__ rs,
    const float* __restrict__ Wq, const float* __restrict__ Wk,
    const float* __restrict__ Wv, f16* __restrict__ Wh)
{
    int bid = blockIdx.x;
    int t = threadIdx.x;

    if (bid >= 2048) {
        // ---- W conversion ----
        int idx = bid - 2048;          // 0..95
        int p = idx >> 5;              // 0..2
        int blk = idx & 31;
        const float* W = (p == 0 ? Wq : (p == 1 ? Wk : Wv));
        f16* dst = Wh + (size_t)p * 262144;
        int base = blk * 256 + t;
#pragma unroll
        for (int i = 0; i < 8; ++i) {
            int e4 = i * 8192 + base;
            float4 v = reinterpret_cast<const float4*>(W)[e4];
            f16x4 pk;
            pk[0] = (f16)v.x; pk[1] = (f16)v.y; pk[2] = (f16)v.z; pk[3] = (f16)v.w;
            reinterpret_cast<f16x4*>(dst)[e4] = pk;
        }
        return;
    }

    // ---- stats for rows 2*pair, 2*pair+1 of tensor ----
    int tensor = bid >> 10;
    int pair = bid & 1023;
    const float* base = (tensor ? style : content) + (size_t)pair * 8192;

    float4 va[4], vb[4];
#pragma unroll
    for (int i = 0; i < 4; ++i) {
        va[i] = reinterpret_cast<const float4*>(base)[t + i * 256];
        vb[i] = reinterpret_cast<const float4*>(base + 4096)[t + i * 256];
    }
    float sA = 0.f, ssA = 0.f, sB = 0.f, ssB = 0.f;
#pragma unroll
    for (int i = 0; i < 4; ++i) {
        sA  += va[i].x + va[i].y + va[i].z + va[i].w;
        ssA += va[i].x * va[i].x + va[i].y * va[i].y + va[i].z * va[i].z + va[i].w * va[i].w;
        sB  += vb[i].x + vb[i].y + vb[i].z + vb[i].w;
        ssB += vb[i].x * vb[i].x + vb[i].y * vb[i].y + vb[i].z * vb[i].z + vb[i].w * vb[i].w;
    }
    for (int off = 32; off > 0; off >>= 1) {
        sA  += __shfl_down(sA, off);
        ssA += __shfl_down(ssA, off);
        sB  += __shfl_down(sB, off);
        ssB += __shfl_down(ssB, off);
    }
    __shared__ float red[4][4];
    int wv = t >> 6;
    if ((t & 63) == 0) {
        red[wv][0] = sA; red[wv][1] = ssA; red[wv][2] = sB; red[wv][3] = ssB;
    }
    __syncthreads();
    if (t == 0) {
        float SA = 0.f, SSA = 0.f, SB = 0.f, SSB = 0.f;
#pragma unroll
        for (int i = 0; i < 4; ++i) {
            SA += red[i][0]; SSA += red[i][1]; SB += red[i][2]; SSB += red[i][3];
        }
        int row0 = tensor * 2048 + pair * 2;
        float mA = SA * (1.f / 4096.f);
        float vA2 = (SSA - 4096.f * mA * mA) * (1.f / 4095.f);
        mu[row0] = mA;
        rs[row0] = rsqrtf(vA2 + 1e-5f);
        float mB = SB * (1.f / 4096.f);
        float vB2 = (SSB - 4096.f * mB * mB) * (1.f / 4095.f);
        mu[row0 + 1] = mB;
        rs[row0 + 1] = rsqrtf(vB2 + 1e-5f);
    }
}

// ---------------- Kernel 2: fused norm + 1x1-conv (Q,K,V), X-resident ------
__global__ __launch_bounds__(512, 4) void qkv_kernel(
    const float* __restrict__ content, const float* __restrict__ style,
    const f16* __restrict__ Wh,
    const float* __restrict__ bq, const float* __restrict__ bk,
    const float* __restrict__ bv,
    const float* __restrict__ mu, const float* __restrict__ rs,
    f16* __restrict__ Qt, f16* __restrict__ Kt, f16* __restrict__ Vc)
{
    int nb = blockIdx.x;
    int y  = blockIdx.y;
    int b = y / 3, p = y % 3;
    int n0 = nb * 64;
    const float* X    = (p == 0 ? content : style) + (size_t)b * 512 * 4096;
    const f16*   Wp   = Wh + (size_t)p * 262144;
    const float* bias = (p == 0 ? bq : (p == 1 ? bk : bv));
    const float* muT  = mu + (p == 0 ? 0 : 2048) + b * 512;
    const float* rsT  = rs + (p == 0 ? 0 : 2048) + b * 512;
    bool norm = (p < 2);

    __shared__ __align__(16) f16 Xt[64][520];

    int t = threadIdx.x;
    int lane = t & 63, w = t >> 6;
    int lg = lane >> 4, li = lane & 15;

#pragma unroll
    for (int i = 0; i < 16; ++i) {
        int c0 = i * 32 + w * 4;
        float x0 = X[(size_t)(c0 + 0) * 4096 + n0 + lane];
        float x1 = X[(size_t)(c0 + 1) * 4096 + n0 + lane];
        float x2 = X[(size_t)(c0 + 2) * 4096 + n0 + lane];
        float x3 = X[(size_t)(c0 + 3) * 4096 + n0 + lane];
        f16x4 pk;
        if (norm) {
            pk[0] = (f16)((x0 - muT[c0 + 0]) * rsT[c0 + 0]);
            pk[1] = (f16)((x1 - muT[c0 + 1]) * rsT[c0 + 1]);
            pk[2] = (f16)((x2 - muT[c0 + 2]) * rsT[c0 + 2]);
            pk[3] = (f16)((x3 - muT[c0 + 3]) * rsT[c0 + 3]);
        } else {
            pk[0] = (f16)x0; pk[1] = (f16)x1; pk[2] = (f16)x2; pk[3] = (f16)x3;
        }
        *reinterpret_cast<f16x4*>(&Xt[lane][c0]) = pk;
    }
    __syncthreads();

    f32x4 acc[4][4];
#pragma unroll
    for (int i = 0; i < 4; ++i)
#pragma unroll
        for (int j = 0; j < 4; ++j)
#pragma unroll
            for (int e = 0; e < 4; ++e) acc[i][j][e] = 0.f;

    const f16* wbase = Wp + (size_t)(w * 64 + li) * 512 + lg * 8;
#pragma unroll 2
    for (int kk = 0; kk < 16; ++kk) {
        f16x8 xf[4], wf[4];
#pragma unroll
        for (int jn = 0; jn < 4; ++jn)
            xf[jn] = *reinterpret_cast<const f16x8*>(&Xt[jn * 16 + li][kk * 32 + lg * 8]);
#pragma unroll
        for (int io = 0; io < 4; ++io)
            wf[io] = *reinterpret_cast<const f16x8*>(wbase + (size_t)io * 16 * 512 + kk * 32);
        if (p < 2) {
#pragma unroll
            for (int io = 0; io < 4; ++io)
#pragma unroll
                for (int jn = 0; jn < 4; ++jn)
                    acc[io][jn] = MFMA16(wf[io], xf[jn], acc[io][jn]);
        } else {
#pragma unroll
            for (int jn = 0; jn < 4; ++jn)
#pragma unroll
                for (int io = 0; io < 4; ++io)
                    acc[jn][io] = MFMA16(xf[jn], wf[io], acc[jn][io]);
        }
    }

    if (p < 2) {
        f16* dst = (p == 0 ? Qt : Kt) + (size_t)b * 4096 * 512;
#pragma unroll
        for (int io = 0; io < 4; ++io) {
            int ob = w * 64 + io * 16 + lg * 4;
            float4 bb = *reinterpret_cast<const float4*>(bias + ob);
#pragma unroll
            for (int jn = 0; jn < 4; ++jn) {
                int n = n0 + jn * 16 + li;
                f16x4 pk;
                pk[0] = (f16)(acc[io][jn][0] + bb.x);
                pk[1] = (f16)(acc[io][jn][1] + bb.y);
                pk[2] = (f16)(acc[io][jn][2] + bb.z);
                pk[3] = (f16)(acc[io][jn][3] + bb.w);
                *reinterpret_cast<f16x4*>(dst + (size_t)n * 512 + ob) = pk;
            }
        }
    } else {
#pragma unroll
        for (int io = 0; io < 4; ++io) {
            int o = w * 64 + io * 16 + li;
            float bb = bias[o];
            f16* dst = Vc + ((size_t)b * 512 + o) * 4096;
#pragma unroll
            for (int jn = 0; jn < 4; ++jn) {
                int n = n0 + jn * 16 + lg * 4;
                f16x4 pk;
#pragma unroll
                for (int e = 0; e < 4; ++e) pk[e] = (f16)(acc[jn][io][e] + bb);
                *reinterpret_cast<f16x4*>(dst + n) = pk;
            }
        }
    }
}

// ---------------- Kernel 3: flash attention, 12-wave balanced, KVBLK=64 ----
// EXACT R8 structure (measured 183 us, 0 bank conflicts). FROZEN.
__global__ __launch_bounds__(768, 3) void attn_kernel(
    const f16* __restrict__ Qt, const f16* __restrict__ Kt,
    const f16* __restrict__ Vc, float* __restrict__ out)
{
    int bid = blockIdx.x;
    int orig = (bid & 7) * 32 + (bid >> 3);   // XCD chunking
    int b = orig >> 6;
    int n0 = (orig & 63) * 64;

    int t = threadIdx.x;
    int lane = t & 63, w = t >> 6;
    int lg = lane >> 4, li = lane & 15;

    __shared__ __align__(16) f16 Km[2][64][528];   // K dbuf [m][c]
    __shared__ __align__(16) f16 Pl[2][64][68];    // P ping-pong [q][m]
    __shared__ __align__(16) float Rrow[2][64];
    __shared__ __align__(16) float Lrow[64];
    __shared__ int Rflag[2][4];

    const f16* Qb = Qt + (size_t)b * 4096 * 512;
    const f16* Kb = Kt + (size_t)b * 4096 * 512;
    const f16* Vb = Vc + (size_t)b * 512 * 4096;

    if (w < 4) {
        int j = w;
        f16x8 qf[16];
#pragma unroll
        for (int kk = 0; kk < 16; ++kk)
            qf[kk] = *reinterpret_cast<const f16x8*>(
                Qb + (size_t)(n0 + j * 16 + li) * 512 + kk * 32 + lg * 8);

#define STAGEK(TILE)                                                           \
        {                                                                      \
            int _db = (TILE) & 1;                                              \
            _Pragma("unroll")                                                  \
            for (int r = 0; r < 16; ++r) {                                     \
                const f16* _gs = Kb + ((size_t)(TILE) * 64 + j * 16 + r) * 512 \
                                 + lane * 8;                                   \
                __builtin_amdgcn_global_load_lds(                              \
                    (const __attribute__((address_space(1))) void*)_gs,        \
                    (__attribute__((address_space(3))) void*)&Km[_db][j * 16 + r][0], \
                    16, 0, 0);                                                 \
            }                                                                  \
        }

        STAGEK(0);
        float Mreg = -3.4e38f, Lreg = 0.f;
        __syncthreads();

        for (int it = 0; it <= 64; ++it) {
            if (it <= 63) {
                int cur = it & 1;
                if (it < 63) STAGEK(it + 1);

                f32x4 s[4];
#pragma unroll
                for (int mg = 0; mg < 4; ++mg)
#pragma unroll
                    for (int e = 0; e < 4; ++e) s[mg][e] = 0.f;
                __builtin_amdgcn_s_setprio(1);
#pragma unroll
                for (int kk = 0; kk < 16; ++kk) {
#pragma unroll
                    for (int mg = 0; mg < 4; ++mg) {
                        f16x8 kf = *reinterpret_cast<const f16x8*>(
                            &Km[cur][mg * 16 + li][kk * 32 + lg * 8]);
                        s[mg] = MFMA16(kf, qf[kk], s[mg]);
                    }
                }
                __builtin_amdgcn_s_setprio(0);

                float mx = s[0][0];
#pragma unroll
                for (int mg = 0; mg < 4; ++mg)
#pragma unroll
                    for (int e = 0; e < 4; ++e) mx = fmaxf(mx, s[mg][e]);
                mx = fmaxf(mx, __shfl_xor(mx, 16));
                mx = fmaxf(mx, __shfl_xor(mx, 32));
                bool needR = (mx - Mreg) > 4.0f;       // defer-max THR=4
                float Mnew = needR ? mx : Mreg;
                float r = needR ? __expf(Mreg - Mnew) : 1.f;
                float p[4][4];
                float sum = 0.f;
#pragma unroll
                for (int mg = 0; mg < 4; ++mg)
#pragma unroll
                    for (int e = 0; e < 4; ++e) {
                        p[mg][e] = __expf(s[mg][e] - Mnew);
                        sum += p[mg][e];
                    }
                sum += __shfl_xor(sum, 16);
                sum += __shfl_xor(sum, 32);
                Lreg = Lreg * r + sum;
                Mreg = Mnew;

#pragma unroll
                for (int mg = 0; mg < 4; ++mg) {
                    f16x4 pk;
#pragma unroll
                    for (int e = 0; e < 4; ++e) pk[e] = (f16)p[mg][e];
                    *reinterpret_cast<f16x4*>(&Pl[cur][j * 16 + li][mg * 16 + lg * 4]) = pk;
                }
                if (lg == 0) Rrow[cur][j * 16 + li] = r;
                int any = __any(needR);
                if (lane == 0) Rflag[cur][j] = any;
                if (it == 63 && lg == 0) Lrow[j * 16 + li] = Lreg;
            }
            __syncthreads();
        }
#undef STAGEK
    } else {
        int pw = w - 4;
        int c0 = pw * 64;
        f32x4 acc[4][4];
#pragma unroll
        for (int fn = 0; fn < 4; ++fn)
#pragma unroll
            for (int fc = 0; fc < 4; ++fc)
#pragma unroll
                for (int e = 0; e < 4; ++e) acc[fn][fc][e] = 0.f;
        f16x8 vfr[4][2];

        __syncthreads();

        for (int it = 0; it <= 64; ++it) {
            if (it >= 1) {
                int pp = (it - 1) & 1;
                if (Rflag[pp][0] | Rflag[pp][1] | Rflag[pp][2] | Rflag[pp][3]) {
#pragma unroll
                    for (int fn = 0; fn < 4; ++fn) {
                        f32x4 rv = *reinterpret_cast<const f32x4*>(&Rrow[pp][fn * 16 + lg * 4]);
#pragma unroll
                        for (int fc = 0; fc < 4; ++fc)
#pragma unroll
                            for (int e = 0; e < 4; ++e) acc[fn][fc][e] *= rv[e];
                    }
                }
                __builtin_amdgcn_s_setprio(1);
#pragma unroll
                for (int fn = 0; fn < 4; ++fn) {
                    f16x8 af0 = *reinterpret_cast<const f16x8*>(&Pl[pp][fn * 16 + li][lg * 8]);
                    f16x8 af1 = *reinterpret_cast<const f16x8*>(&Pl[pp][fn * 16 + li][32 + lg * 8]);
#pragma unroll
                    for (int fc = 0; fc < 4; ++fc) {
                        acc[fn][fc] = MFMA16(af0, vfr[fc][0], acc[fn][fc]);
                        acc[fn][fc] = MFMA16(af1, vfr[fc][1], acc[fn][fc]);
                    }
                }
                __builtin_amdgcn_s_setprio(0);
            }
            if (it <= 63) {
                const f16* vs = Vb + (size_t)(c0 + li) * 4096 + it * 64 + lg * 8;
#pragma unroll
                for (int fc = 0; fc < 4; ++fc) {
                    vfr[fc][0] = *reinterpret_cast<const f16x8*>(vs + (size_t)fc * 16 * 4096);
                    vfr[fc][1] = *reinterpret_cast<const f16x8*>(vs + (size_t)fc * 16 * 4096 + 32);
                }
            }
            __syncthreads();
        }

        float* ob = out + (size_t)b * 512 * 4096;
#pragma unroll
        for (int fn = 0; fn < 4; ++fn) {
            f32x4 lv = *reinterpret_cast<const f32x4*>(&Lrow[fn * 16 + lg * 4]);
            f32x4 linv;
#pragma unroll
            for (int e = 0; e < 4; ++e) linv[e] = 1.f / lv[e];
#pragma unroll
            for (int fc = 0; fc < 4; ++fc) {
                int c = c0 + fc * 16 + li;
                f32x4 o4;
#pragma unroll
                for (int e = 0; e < 4; ++e) o4[e] = acc[fn][fc][e] * linv[e];
                *reinterpret_cast<f32x4*>(ob + (size_t)c * 4096 + n0 + fn * 16 + lg * 4) = o4;
            }
        }
    }
}

// ---------------------------------------------------------------------------
extern "C" void kernel_launch(void* const* d_in, const int* in_sizes, int n_in,
                              void* d_out, int out_size, void* d_ws, size_t ws_size,
                              hipStream_t stream)
{
    const float* content = (const float*)d_in[0];
    const float* style   = (const float*)d_in[1];
    const float* Wq = (const float*)d_in[2];
    const float* bq = (const float*)d_in[3];
    const float* Wk = (const float*)d_in[4];
    const float* bk = (const float*)d_in[5];
    const float* Wv = (const float*)d_in[6];
    const float* bv = (const float*)d_in[7];
    float* out = (float*)d_out;

    const size_t TEN = (size_t)4 * 4096 * 512;
    f16* Qt = (f16*)d_ws;
    f16* Kt = Qt + TEN;
    f16* Vc = Kt + TEN;
    float* mu = (float*)(Vc + TEN);
    float* rs = mu + 4096;
    f16* Wh = (f16*)(rs + 4096);             // 3 x 512 x 512 f16 = 1.5 MB

    hipLaunchKernelGGL(stats_kernel, dim3(2144), dim3(256), 0, stream,
                       content, style, mu, rs, Wq, Wk, Wv, Wh);
    hipLaunchKernelGGL(qkv_kernel, dim3(64, 12), dim3(512), 0, stream,
                       content, style, Wh, bq, bk, bv, mu, rs, Qt, Kt, Vc);
    hipLaunchKernelGGL(attn_kernel, dim3(256), dim3(768), 0, stream,
                       Qt, Kt, Vc, out);
}

// Round 14
// 248.285 us; speedup vs baseline: 1.5676x; 1.5676x over previous
//
#include <hip/hip_runtime.h>

typedef _Float16 f16;
typedef _Float16 f16x4 __attribute__((ext_vector_type(4)));
typedef _Float16 f16x8 __attribute__((ext_vector_type(8)));
typedef float f32x4 __attribute__((ext_vector_type(4)));

#define MFMA16(a, b, c) __builtin_amdgcn_mfma_f32_16x16x32_f16(a, b, c, 0, 0, 0)

// ---------------- Kernel 1: stats (2 rows/block) + W->f16 conversion -------
// blocks 0..2047   : per-(tensor,row-pair) mean / inv-std, 32 KB contiguous
// blocks 2048..2143: W -> f16 conversion (3 x 32 blocks)
__global__ __launch_bounds__(256) void stats_kernel(
    const float* __restrict__ content, const float* __restrict__ style,
    float* __restrict__ mu, float* __restrict__ rs,
    const float* __restrict__ Wq, const float* __restrict__ Wk,
    const float* __restrict__ Wv, f16* __restrict__ Wh)
{
    int bid = blockIdx.x;
    int t = threadIdx.x;

    if (bid >= 2048) {
        // ---- W conversion ----
        int idx = bid - 2048;          // 0..95
        int p = idx >> 5;              // 0..2
        int blk = idx & 31;
        const float* W = (p == 0 ? Wq : (p == 1 ? Wk : Wv));
        f16* dst = Wh + (size_t)p * 262144;
        int base = blk * 256 + t;
#pragma unroll
        for (int i = 0; i < 8; ++i) {
            int e4 = i * 8192 + base;
            float4 v = reinterpret_cast<const float4*>(W)[e4];
            f16x4 pk;
            pk[0] = (f16)v.x; pk[1] = (f16)v.y; pk[2] = (f16)v.z; pk[3] = (f16)v.w;
            reinterpret_cast<f16x4*>(dst)[e4] = pk;
        }
        return;
    }

    // ---- stats for rows 2*pair, 2*pair+1 of tensor ----
    int tensor = bid >> 10;
    int pair = bid & 1023;
    const float* base = (tensor ? style : content) + (size_t)pair * 8192;

    float4 va[4], vb[4];
#pragma unroll
    for (int i = 0; i < 4; ++i) {
        va[i] = reinterpret_cast<const float4*>(base)[t + i * 256];
        vb[i] = reinterpret_cast<const float4*>(base + 4096)[t + i * 256];
    }
    float sA = 0.f, ssA = 0.f, sB = 0.f, ssB = 0.f;
#pragma unroll
    for (int i = 0; i < 4; ++i) {
        sA  += va[i].x + va[i].y + va[i].z + va[i].w;
        ssA += va[i].x * va[i].x + va[i].y * va[i].y + va[i].z * va[i].z + va[i].w * va[i].w;
        sB  += vb[i].x + vb[i].y + vb[i].z + vb[i].w;
        ssB += vb[i].x * vb[i].x + vb[i].y * vb[i].y + vb[i].z * vb[i].z + vb[i].w * vb[i].w;
    }
    for (int off = 32; off > 0; off >>= 1) {
        sA  += __shfl_down(sA, off);
        ssA += __shfl_down(ssA, off);
        sB  += __shfl_down(sB, off);
        ssB += __shfl_down(ssB, off);
    }
    __shared__ float red[4][4];
    int wv = t >> 6;
    if ((t & 63) == 0) {
        red[wv][0] = sA; red[wv][1] = ssA; red[wv][2] = sB; red[wv][3] = ssB;
    }
    __syncthreads();
    if (t == 0) {
        float SA = 0.f, SSA = 0.f, SB = 0.f, SSB = 0.f;
#pragma unroll
        for (int i = 0; i < 4; ++i) {
            SA += red[i][0]; SSA += red[i][1]; SB += red[i][2]; SSB += red[i][3];
        }
        int row0 = tensor * 2048 + pair * 2;
        float mA = SA * (1.f / 4096.f);
        float vA2 = (SSA - 4096.f * mA * mA) * (1.f / 4095.f);
        mu[row0] = mA;
        rs[row0] = rsqrtf(vA2 + 1e-5f);
        float mB = SB * (1.f / 4096.f);
        float vB2 = (SSB - 4096.f * mB * mB) * (1.f / 4095.f);
        mu[row0 + 1] = mB;
        rs[row0 + 1] = rsqrtf(vB2 + 1e-5f);
    }
}

// ---------------- Kernel 2: fused norm + 1x1-conv (Q,K,V), X-resident ------
// R9-exact configuration (measured ~37 us): launch_bounds(512,3), no unroll-2.
__global__ __launch_bounds__(512, 3) void qkv_kernel(
    const float* __restrict__ content, const float* __restrict__ style,
    const f16* __restrict__ Wh,
    const float* __restrict__ bq, const float* __restrict__ bk,
    const float* __restrict__ bv,
    const float* __restrict__ mu, const float* __restrict__ rs,
    f16* __restrict__ Qt, f16* __restrict__ Kt, f16* __restrict__ Vc)
{
    int nb = blockIdx.x;
    int y  = blockIdx.y;
    int b = y / 3, p = y % 3;
    int n0 = nb * 64;
    const float* X    = (p == 0 ? content : style) + (size_t)b * 512 * 4096;
    const f16*   Wp   = Wh + (size_t)p * 262144;
    const float* bias = (p == 0 ? bq : (p == 1 ? bk : bv));
    const float* muT  = mu + (p == 0 ? 0 : 2048) + b * 512;
    const float* rsT  = rs + (p == 0 ? 0 : 2048) + b * 512;
    bool norm = (p < 2);

    __shared__ __align__(16) f16 Xt[64][520];

    int t = threadIdx.x;
    int lane = t & 63, w = t >> 6;
    int lg = lane >> 4, li = lane & 15;

#pragma unroll
    for (int i = 0; i < 16; ++i) {
        int c0 = i * 32 + w * 4;
        float x0 = X[(size_t)(c0 + 0) * 4096 + n0 + lane];
        float x1 = X[(size_t)(c0 + 1) * 4096 + n0 + lane];
        float x2 = X[(size_t)(c0 + 2) * 4096 + n0 + lane];
        float x3 = X[(size_t)(c0 + 3) * 4096 + n0 + lane];
        f16x4 pk;
        if (norm) {
            pk[0] = (f16)((x0 - muT[c0 + 0]) * rsT[c0 + 0]);
            pk[1] = (f16)((x1 - muT[c0 + 1]) * rsT[c0 + 1]);
            pk[2] = (f16)((x2 - muT[c0 + 2]) * rsT[c0 + 2]);
            pk[3] = (f16)((x3 - muT[c0 + 3]) * rsT[c0 + 3]);
        } else {
            pk[0] = (f16)x0; pk[1] = (f16)x1; pk[2] = (f16)x2; pk[3] = (f16)x3;
        }
        *reinterpret_cast<f16x4*>(&Xt[lane][c0]) = pk;
    }
    __syncthreads();

    f32x4 acc[4][4];
#pragma unroll
    for (int i = 0; i < 4; ++i)
#pragma unroll
        for (int j = 0; j < 4; ++j)
#pragma unroll
            for (int e = 0; e < 4; ++e) acc[i][j][e] = 0.f;

    const f16* wbase = Wp + (size_t)(w * 64 + li) * 512 + lg * 8;
    for (int kk = 0; kk < 16; ++kk) {
        f16x8 xf[4], wf[4];
#pragma unroll
        for (int jn = 0; jn < 4; ++jn)
            xf[jn] = *reinterpret_cast<const f16x8*>(&Xt[jn * 16 + li][kk * 32 + lg * 8]);
#pragma unroll
        for (int io = 0; io < 4; ++io)
            wf[io] = *reinterpret_cast<const f16x8*>(wbase + (size_t)io * 16 * 512 + kk * 32);
        if (p < 2) {
#pragma unroll
            for (int io = 0; io < 4; ++io)
#pragma unroll
                for (int jn = 0; jn < 4; ++jn)
                    acc[io][jn] = MFMA16(wf[io], xf[jn], acc[io][jn]);
        } else {
#pragma unroll
            for (int jn = 0; jn < 4; ++jn)
#pragma unroll
                for (int io = 0; io < 4; ++io)
                    acc[jn][io] = MFMA16(xf[jn], wf[io], acc[jn][io]);
        }
    }

    if (p < 2) {
        f16* dst = (p == 0 ? Qt : Kt) + (size_t)b * 4096 * 512;
#pragma unroll
        for (int io = 0; io < 4; ++io) {
            int ob = w * 64 + io * 16 + lg * 4;
            float4 bb = *reinterpret_cast<const float4*>(bias + ob);
#pragma unroll
            for (int jn = 0; jn < 4; ++jn) {
                int n = n0 + jn * 16 + li;
                f16x4 pk;
                pk[0] = (f16)(acc[io][jn][0] + bb.x);
                pk[1] = (f16)(acc[io][jn][1] + bb.y);
                pk[2] = (f16)(acc[io][jn][2] + bb.z);
                pk[3] = (f16)(acc[io][jn][3] + bb.w);
                *reinterpret_cast<f16x4*>(dst + (size_t)n * 512 + ob) = pk;
            }
        }
    } else {
#pragma unroll
        for (int io = 0; io < 4; ++io) {
            int o = w * 64 + io * 16 + li;
            float bb = bias[o];
            f16* dst = Vc + ((size_t)b * 512 + o) * 4096;
#pragma unroll
            for (int jn = 0; jn < 4; ++jn) {
                int n = n0 + jn * 16 + lg * 4;
                f16x4 pk;
#pragma unroll
                for (int e = 0; e < 4; ++e) pk[e] = (f16)(acc[jn][io][e] + bb);
                *reinterpret_cast<f16x4*>(dst + n) = pk;
            }
        }
    }
}

// ---------------- Kernel 3: flash attention, 12-wave balanced, KVBLK=64 ----
// EXACT R8 structure (measured 183 us, 0 bank conflicts). FROZEN.
__global__ __launch_bounds__(768, 3) void attn_kernel(
    const f16* __restrict__ Qt, const f16* __restrict__ Kt,
    const f16* __restrict__ Vc, float* __restrict__ out)
{
    int bid = blockIdx.x;
    int orig = (bid & 7) * 32 + (bid >> 3);   // XCD chunking
    int b = orig >> 6;
    int n0 = (orig & 63) * 64;

    int t = threadIdx.x;
    int lane = t & 63, w = t >> 6;
    int lg = lane >> 4, li = lane & 15;

    __shared__ __align__(16) f16 Km[2][64][528];   // K dbuf [m][c]
    __shared__ __align__(16) f16 Pl[2][64][68];    // P ping-pong [q][m]
    __shared__ __align__(16) float Rrow[2][64];
    __shared__ __align__(16) float Lrow[64];
    __shared__ int Rflag[2][4];

    const f16* Qb = Qt + (size_t)b * 4096 * 512;
    const f16* Kb = Kt + (size_t)b * 4096 * 512;
    const f16* Vb = Vc + (size_t)b * 512 * 4096;

    if (w < 4) {
        int j = w;
        f16x8 qf[16];
#pragma unroll
        for (int kk = 0; kk < 16; ++kk)
            qf[kk] = *reinterpret_cast<const f16x8*>(
                Qb + (size_t)(n0 + j * 16 + li) * 512 + kk * 32 + lg * 8);

#define STAGEK(TILE)                                                           \
        {                                                                      \
            int _db = (TILE) & 1;                                              \
            _Pragma("unroll")                                                  \
            for (int r = 0; r < 16; ++r) {                                     \
                const f16* _gs = Kb + ((size_t)(TILE) * 64 + j * 16 + r) * 512 \
                                 + lane * 8;                                   \
                __builtin_amdgcn_global_load_lds(                              \
                    (const __attribute__((address_space(1))) void*)_gs,        \
                    (__attribute__((address_space(3))) void*)&Km[_db][j * 16 + r][0], \
                    16, 0, 0);                                                 \
            }                                                                  \
        }

        STAGEK(0);
        float Mreg = -3.4e38f, Lreg = 0.f;
        __syncthreads();

        for (int it = 0; it <= 64; ++it) {
            if (it <= 63) {
                int cur = it & 1;
                if (it < 63) STAGEK(it + 1);

                f32x4 s[4];
#pragma unroll
                for (int mg = 0; mg < 4; ++mg)
#pragma unroll
                    for (int e = 0; e < 4; ++e) s[mg][e] = 0.f;
                __builtin_amdgcn_s_setprio(1);
#pragma unroll
                for (int kk = 0; kk < 16; ++kk) {
#pragma unroll
                    for (int mg = 0; mg < 4; ++mg) {
                        f16x8 kf = *reinterpret_cast<const f16x8*>(
                            &Km[cur][mg * 16 + li][kk * 32 + lg * 8]);
                        s[mg] = MFMA16(kf, qf[kk], s[mg]);
                    }
                }
                __builtin_amdgcn_s_setprio(0);

                float mx = s[0][0];
#pragma unroll
                for (int mg = 0; mg < 4; ++mg)
#pragma unroll
                    for (int e = 0; e < 4; ++e) mx = fmaxf(mx, s[mg][e]);
                mx = fmaxf(mx, __shfl_xor(mx, 16));
                mx = fmaxf(mx, __shfl_xor(mx, 32));
                bool needR = (mx - Mreg) > 4.0f;       // defer-max THR=4
                float Mnew = needR ? mx : Mreg;
                float r = needR ? __expf(Mreg - Mnew) : 1.f;
                float p[4][4];
                float sum = 0.f;
#pragma unroll
                for (int mg = 0; mg < 4; ++mg)
#pragma unroll
                    for (int e = 0; e < 4; ++e) {
                        p[mg][e] = __expf(s[mg][e] - Mnew);
                        sum += p[mg][e];
                    }
                sum += __shfl_xor(sum, 16);
                sum += __shfl_xor(sum, 32);
                Lreg = Lreg * r + sum;
                Mreg = Mnew;

#pragma unroll
                for (int mg = 0; mg < 4; ++mg) {
                    f16x4 pk;
#pragma unroll
                    for (int e = 0; e < 4; ++e) pk[e] = (f16)p[mg][e];
                    *reinterpret_cast<f16x4*>(&Pl[cur][j * 16 + li][mg * 16 + lg * 4]) = pk;
                }
                if (lg == 0) Rrow[cur][j * 16 + li] = r;
                int any = __any(needR);
                if (lane == 0) Rflag[cur][j] = any;
                if (it == 63 && lg == 0) Lrow[j * 16 + li] = Lreg;
            }
            __syncthreads();
        }
#undef STAGEK
    } else {
        int pw = w - 4;
        int c0 = pw * 64;
        f32x4 acc[4][4];
#pragma unroll
        for (int fn = 0; fn < 4; ++fn)
#pragma unroll
            for (int fc = 0; fc < 4; ++fc)
#pragma unroll
                for (int e = 0; e < 4; ++e) acc[fn][fc][e] = 0.f;
        f16x8 vfr[4][2];

        __syncthreads();

        for (int it = 0; it <= 64; ++it) {
            if (it >= 1) {
                int pp = (it - 1) & 1;
                if (Rflag[pp][0] | Rflag[pp][1] | Rflag[pp][2] | Rflag[pp][3]) {
#pragma unroll
                    for (int fn = 0; fn < 4; ++fn) {
                        f32x4 rv = *reinterpret_cast<const f32x4*>(&Rrow[pp][fn * 16 + lg * 4]);
#pragma unroll
                        for (int fc = 0; fc < 4; ++fc)
#pragma unroll
                            for (int e = 0; e < 4; ++e) acc[fn][fc][e] *= rv[e];
                    }
                }
                __builtin_amdgcn_s_setprio(1);
#pragma unroll
                for (int fn = 0; fn < 4; ++fn) {
                    f16x8 af0 = *reinterpret_cast<const f16x8*>(&Pl[pp][fn * 16 + li][lg * 8]);
                    f16x8 af1 = *reinterpret_cast<const f16x8*>(&Pl[pp][fn * 16 + li][32 + lg * 8]);
#pragma unroll
                    for (int fc = 0; fc < 4; ++fc) {
                        acc[fn][fc] = MFMA16(af0, vfr[fc][0], acc[fn][fc]);
                        acc[fn][fc] = MFMA16(af1, vfr[fc][1], acc[fn][fc]);
                    }
                }
                __builtin_amdgcn_s_setprio(0);
            }
            if (it <= 63) {
                const f16* vs = Vb + (size_t)(c0 + li) * 4096 + it * 64 + lg * 8;
#pragma unroll
                for (int fc = 0; fc < 4; ++fc) {
                    vfr[fc][0] = *reinterpret_cast<const f16x8*>(vs + (size_t)fc * 16 * 4096);
                    vfr[fc][1] = *reinterpret_cast<const f16x8*>(vs + (size_t)fc * 16 * 4096 + 32);
                }
            }
            __syncthreads();
        }

        float* ob = out + (size_t)b * 512 * 4096;
#pragma unroll
        for (int fn = 0; fn < 4; ++fn) {
            f32x4 lv = *reinterpret_cast<const f32x4*>(&Lrow[fn * 16 + lg * 4]);
            f32x4 linv;
#pragma unroll
            for (int e = 0; e < 4; ++e) linv[e] = 1.f / lv[e];
#pragma unroll
            for (int fc = 0; fc < 4; ++fc) {
                int c = c0 + fc * 16 + li;
                f32x4 o4;
#pragma unroll
                for (int e = 0; e < 4; ++e) o4[e] = acc[fn][fc][e] * linv[e];
                *reinterpret_cast<f32x4*>(ob + (size_t)c * 4096 + n0 + fn * 16 + lg * 4) = o4;
            }
        }
    }
}

// ---------------------------------------------------------------------------
extern "C" void kernel_launch(void* const* d_in, const int* in_sizes, int n_in,
                              void* d_out, int out_size, void* d_ws, size_t ws_size,
                              hipStream_t stream)
{
    const float* content = (const float*)d_in[0];
    const float* style   = (const float*)d_in[1];
    const float* Wq = (const float*)d_in[2];
    const float* bq = (const float*)d_in[3];
    const float* Wk = (const float*)d_in[4];
    const float* bk = (const float*)d_in[5];
    const float* Wv = (const float*)d_in[6];
    const float* bv = (const float*)d_in[7];
    float* out = (float*)d_out;

    const size_t TEN = (size_t)4 * 4096 * 512;
    f16* Qt = (f16*)d_ws;
    f16* Kt = Qt + TEN;
    f16* Vc = Kt + TEN;
    float* mu = (float*)(Vc + TEN);
    float* rs = mu + 4096;
    f16* Wh = (f16*)(rs + 4096);             // 3 x 512 x 512 f16 = 1.5 MB

    hipLaunchKernelGGL(stats_kernel, dim3(2144), dim3(256), 0, stream,
                       content, style, mu, rs, Wq, Wk, Wv, Wh);
    hipLaunchKernelGGL(qkv_kernel, dim3(64, 12), dim3(512), 0, stream,
                       content, style, Wh, bq, bk, bv, mu, rs, Qt, Kt, Vc);
    hipLaunchKernelGGL(attn_kernel, dim3(256), dim3(768), 0, stream,
                       Qt, Kt, Vc, out);
}